// Round 14
// baseline (835.625 us; speedup 1.0000x reference)
//
#include <hip/hip_runtime.h>
#include <cstddef>
#include <cstdint>

#define NUC 40000
#define NIC 60000
#define NC  100000

typedef short  short8 __attribute__((ext_vector_type(8)));
typedef float  f32x4  __attribute__((ext_vector_type(4)));
typedef unsigned short us;

__device__ __forceinline__ float lrelu(float x) { return x >= 0.f ? x : 0.01f * x; }

__device__ __forceinline__ us f2bf(float f) {
    unsigned int u = __builtin_bit_cast(unsigned int, f);
    u += 0x7fffu + ((u >> 16) & 1u);           // RNE
    return (us)(u >> 16);
}
__device__ __forceinline__ float bf2f(unsigned int v) {
    return __builtin_bit_cast(float, v << 16);
}
__device__ __forceinline__ unsigned pk2(float a, float b) {
    return (unsigned)f2bf(a) | ((unsigned)f2bf(b) << 16);
}

// direct global->LDS DMA, 16B/lane; LDS dest = wave-uniform base + lane*16
__device__ __forceinline__ void gl_lds16(const us* g, us* l) {
    __builtin_amdgcn_global_load_lds(
        (const __attribute__((address_space(1))) unsigned int*)g,
        (__attribute__((address_space(3))) unsigned int*)l,
        16, 0, 0);
}

// counted-wait + raw barrier (T4); sched_barrier(0) fences per learn_hip rule #18.
#define CBAR(N)                                                               \
    asm volatile("s_waitcnt vmcnt(" #N ") lgkmcnt(0)" ::: "memory");          \
    __builtin_amdgcn_sched_barrier(0);                                        \
    __builtin_amdgcn_s_barrier();                                             \
    __builtin_amdgcn_sched_barrier(0);
#define TBAR()                                                                \
    __builtin_amdgcn_sched_barrier(0);                                        \
    __builtin_amdgcn_s_barrier();                                             \
    __builtin_amdgcn_sched_barrier(0);

enum { EPI_NONE = 0, EPI_BIAS = 1, EPI_LIN = 2, EPI_G = 3, EPI_NORM = 4, EPI_CLIN = 5 };

struct GPair {
    const void* A[2]; const us* W[2];
    const float* bias[2]; const float* extra[2];
    void* C[2]; int K[2]; int M;
    // EPI_CLIN extras: second (lin) weight/bias/output
    const us* W2[2]; const float* b2[2]; void* C2[2];
};

// ===== MFMA GEMM pair, counted-vmcnt raw-barrier pipeline (WN=4: 128x256) =====
// R12-proven: NBUF=2, depth-2 A reg prefetch, CBAR 8/12/0. Unchanged.
template<int EPI, bool A_BF16, bool OUT_BF16, int WN>
__global__ __launch_bounds__(256, 2)
void gemm_pair(GPair P)
{
    static_assert(WN == 4, "only WN=4 in use");
    constexpr bool CLIN = (EPI == EPI_CLIN);
    constexpr int BM  = 128;
    constexpr int BN  = 256;
    constexpr int MI  = 8;
    constexpr int IA  = BM / 64;
    constexpr int IB  = BN / 64;
    constexpr int NL  = CLIN ? 2 : 1;

    __shared__ __align__(16) us Al[2][BM][32];
    __shared__ __align__(16) us Bl[2][BN][32];
    __shared__ __align__(16) us Ll[CLIN ? 2 : 1][64][32];

    const int p = blockIdx.y;
    const void* Av = P.A[p];
    const us*   Wt = P.W[p];
    const float* bias  = P.bias[p];
    const float* extra = P.extra[p];
    void* Cv = P.C[p];
    const us*    Lt  = P.W2[p];
    const float* lb  = P.b2[p];
    void*        C2v = P.C2[p];
    const int M = P.M, K = P.K[p];

    const int t = threadIdx.x;
    const int wave = t >> 6, lane = t & 63;
    const int wn = wave;
    const int row0 = blockIdx.x * BM;
    const int fr = lane & 15, fk = lane >> 4;

    const float* Af = (const float*)Av;
    const us*    Ab = (const us*)Av;

    float4 sA[4], sB[4];
    f32x4  acc[MI][4] = {};
    f32x4  acc_l[NL][4] = {};

#define STAGE_DMA(BUF, K0)                                                     \
    {   const int k0_ = (K0);                                                  \
        _Pragma("unroll")                                                      \
        for (int i = 0; i < IB; ++i) {                                         \
            int rb = (wave * IB + i) * 16;                                     \
            int r  = rb + (lane >> 2);                                         \
            int cs = (lane & 3) ^ (r & 3);                                     \
            gl_lds16(&Wt[(size_t)r * K + k0_ + cs * 8], &Bl[BUF][rb][0]);      \
        }                                                                      \
        if constexpr (A_BF16) {                                                \
            _Pragma("unroll")                                                  \
            for (int i = 0; i < IA; ++i) {                                     \
                int rb = (wave * IA + i) * 16;                                 \
                int r  = rb + (lane >> 2);                                     \
                int cs = (lane & 3) ^ (r & 3);                                 \
                int rc = min(row0 + r, M - 1);                                 \
                gl_lds16(&Ab[(size_t)rc * K + k0_ + cs * 8], &Al[BUF][rb][0]); \
            }                                                                  \
        }                                                                      \
        if constexpr (CLIN) {                                                  \
            int rb = wave * 16;                                                \
            int r  = rb + (lane >> 2);                                         \
            int cs = (lane & 3) ^ (r & 3);                                     \
            gl_lds16(&Lt[(size_t)r * K + k0_ + cs * 8], &Ll[BUF][rb][0]);      \
        }                                                                      \
    }

#define AF_LOAD(SL, K0)                                                        \
    {   const int k0_ = (K0);                                                  \
        int r = t >> 1;                                                        \
        int rc = min(row0 + r, M - 1);                                         \
        const float* ap = &Af[(size_t)rc * K + k0_ + (t & 1) * 16];            \
        SL[0] = *(const float4*)ap;                                            \
        SL[1] = *(const float4*)(ap + 4);                                      \
        SL[2] = *(const float4*)(ap + 8);                                      \
        SL[3] = *(const float4*)(ap + 12);                                     \
    }

#define AF_WRITE(SL, BUF)                                                      \
    {   int r  = t >> 1;                                                       \
        int cb = (t & 1) * 2;                                                  \
        uint4 k0v, k1v;                                                        \
        k0v.x = pk2(SL[0].x, SL[0].y);  k0v.y = pk2(SL[0].z, SL[0].w);         \
        k0v.z = pk2(SL[1].x, SL[1].y);  k0v.w = pk2(SL[1].z, SL[1].w);         \
        k1v.x = pk2(SL[2].x, SL[2].y);  k1v.y = pk2(SL[2].z, SL[2].w);         \
        k1v.z = pk2(SL[3].x, SL[3].y);  k1v.w = pk2(SL[3].z, SL[3].w);         \
        *(uint4*)&Al[BUF][r][((cb)     ^ (r & 3)) * 8] = k0v;                  \
        *(uint4*)&Al[BUF][r][((cb + 1) ^ (r & 3)) * 8] = k1v;                  \
    }

#define COMPUTE(BUF)                                                           \
    {   short8 a_[MI], b_[4];                                                  \
        const int ch = (fk ^ (fr & 3)) * 8;                                    \
        _Pragma("unroll")                                                      \
        for (int i = 0; i < MI; ++i)                                           \
            a_[i] = *(const short8*)&Al[BUF][i * 16 + fr][ch];                 \
        _Pragma("unroll")                                                      \
        for (int n = 0; n < 4; ++n)                                            \
            b_[n] = *(const short8*)&Bl[BUF][wn * 64 + n * 16 + fr][ch];       \
        _Pragma("unroll")                                                      \
        for (int i = 0; i < MI; ++i)                                           \
            _Pragma("unroll")                                                  \
            for (int n = 0; n < 4; ++n)                                        \
                acc[i][n] = __builtin_amdgcn_mfma_f32_16x16x32_bf16(           \
                    a_[i], b_[n], acc[i][n], 0, 0, 0);                         \
        if constexpr (CLIN) {                                                  \
            short8 bl_[4];                                                     \
            _Pragma("unroll")                                                  \
            for (int n = 0; n < 4; ++n)                                        \
                bl_[n] = *(const short8*)&Ll[BUF][n * 16 + fr][ch];            \
            _Pragma("unroll")                                                  \
            for (int i = 0; i < MI; ++i) {                                     \
                if ((i >> 1) == wave) {   /* wave-uniform; i is literal */     \
                    _Pragma("unroll")                                          \
                    for (int n = 0; n < 4; ++n)                                \
                        acc_l[i & 1][n] =                                      \
                            __builtin_amdgcn_mfma_f32_16x16x32_bf16(           \
                                a_[i], bl_[n], acc_l[i & 1][n], 0, 0, 0);      \
                }                                                              \
            }                                                                  \
        }                                                                      \
    }

    const int NT = K / 32;

    if constexpr (!A_BF16) {
        AF_LOAD(sA, 0)
        AF_LOAD(sB, 32)
        AF_WRITE(sA, 0)
        STAGE_DMA(0, 0)
        STAGE_DMA(1, 32)
        AF_LOAD(sA, 64)
        CBAR(8)
        COMPUTE(0)
        TBAR()
        for (int tt = 1; tt + 2 < NT; ++tt) {
            STAGE_DMA((tt + 1) & 1, (tt + 1) * 32);
            if (tt & 1) {
                AF_WRITE(sB, 1)
                AF_LOAD(sB, (tt + 2) * 32)
            } else {
                AF_WRITE(sA, 0)
                AF_LOAD(sA, (tt + 2) * 32)
            }
            CBAR(12)
            COMPUTE(tt & 1)
            TBAR()
        }
        STAGE_DMA((NT - 1) & 1, (NT - 1) * 32);
        AF_WRITE(sA, 0)
        CBAR(8)
        COMPUTE(0)
        TBAR()
        AF_WRITE(sB, 1)
        CBAR(0)
        COMPUTE(1)
        TBAR()
    } else {
        STAGE_DMA(0, 0)
        STAGE_DMA(1, 32)
        if constexpr (CLIN) { CBAR(7) } else { CBAR(6) }
        COMPUTE(0)
        TBAR()
        for (int tt = 1; tt + 1 < NT; ++tt) {
            STAGE_DMA((tt + 1) & 1, (tt + 1) * 32);
            if constexpr (CLIN) { CBAR(7) } else { CBAR(6) }
            COMPUTE(tt & 1)
            TBAR()
        }
        CBAR(0)
        COMPUTE((NT - 1) & 1)
        TBAR()
    }
#undef STAGE_DMA
#undef AF_LOAD
#undef AF_WRITE
#undef COMPUTE

    float* Cf = (float*)Cv;
    us*    Cb = (us*)Cv;

    if constexpr (EPI == EPI_NORM) {
        float (*snorm)[BM] = (float(*)[BM])Al;
        float bv[4];
        #pragma unroll
        for (int nn = 0; nn < 4; ++nn) bv[nn] = bias[wn * 64 + nn * 16 + fr];
        #pragma unroll
        for (int i = 0; i < MI; ++i) {
            #pragma unroll
            for (int q = 0; q < 4; ++q) {
                float pp = 0.f;
                #pragma unroll
                for (int nn = 0; nn < 4; ++nn) {
                    float v = acc[i][nn][q] + bv[nn];
                    acc[i][nn][q] = v;
                    pp += v * v;
                }
                pp += __shfl_xor(pp, 1); pp += __shfl_xor(pp, 2);
                pp += __shfl_xor(pp, 4); pp += __shfl_xor(pp, 8);
                if (fr == 0) snorm[wn][i * 16 + fk * 4 + q] = pp;
            }
        }
        __syncthreads();
        #pragma unroll
        for (int i = 0; i < MI; ++i) {
            #pragma unroll
            for (int q = 0; q < 4; ++q) {
                int rl = i * 16 + fk * 4 + q;
                int r  = row0 + rl;
                if (r >= M) continue;
                float tot = snorm[0][rl] + snorm[1][rl] + snorm[2][rl] + snorm[3][rl];
                float scale = 1.f / fmaxf(sqrtf(tot), 1e-12f);
                #pragma unroll
                for (int nn = 0; nn < 4; ++nn)
                    Cb[(size_t)r * 256 + wn * 64 + nn * 16 + fr] =
                        f2bf(acc[i][nn][q] * scale);
            }
        }
        return;
    }

    if constexpr (CLIN) {
        #pragma unroll
        for (int i = 0; i < MI; ++i) {
            #pragma unroll
            for (int q = 0; q < 4; ++q) {
                int r = row0 + i * 16 + fk * 4 + q;
                if (r >= M) continue;
                #pragma unroll
                for (int n = 0; n < 4; ++n)
                    Cb[(size_t)r * 256 + wn * 64 + n * 16 + fr] = f2bf(acc[i][n][q]);
            }
        }
        us* XHb = (us*)C2v;
        #pragma unroll
        for (int i = 0; i < NL; ++i) {
            #pragma unroll
            for (int q = 0; q < 4; ++q) {
                int r = row0 + wave * 32 + i * 16 + fk * 4 + q;
                if (r >= M) continue;
                #pragma unroll
                for (int n = 0; n < 4; ++n) {
                    int c = n * 16 + fr;
                    float v = lrelu(acc_l[i][n][q] + lb[c]) +
                              extra[(size_t)r * 64 + c];
                    XHb[(size_t)r * 64 + c] = f2bf(v);
                }
            }
        }
        return;
    }

    #pragma unroll
    for (int i = 0; i < MI; ++i) {
        #pragma unroll
        for (int q = 0; q < 4; ++q) {
            int r = row0 + i * 16 + fk * 4 + q;
            if (r >= M) continue;
            #pragma unroll
            for (int n = 0; n < 4; ++n) {
                int c = wn * 64 + n * 16 + fr;
                float v = acc[i][n][q];
                if constexpr (EPI == EPI_BIAS) v += bias[c];
                if constexpr (OUT_BF16) Cb[(size_t)r * BN + c] = f2bf(v);
                else                    Cf[(size_t)r * BN + c] = v;
            }
        }
    }
}

// ======== fused gather + g-GEMM pair, K=256 (layer 1); XH bf16 — unchanged ========
struct GG256 {
    const us* Mb[2]; const us* Gt[2]; const float* gb[2];
    const us* XH[2]; us* Xout[2];
};
__global__ __launch_bounds__(512)
void gather_g256(GG256 P, const int* __restrict__ rowptr,
                 const int* __restrict__ col, int n)
{
    __shared__ __align__(16) us Hl[64][256];
    __shared__ __align__(16) us Bw[64][256];
    const int p = blockIdx.y;
    const us* Mb = P.Mb[p];
    const int t = threadIdx.x, wave = t >> 6, lane = t & 63;
    const int row0 = blockIdx.x * 64;

    #pragma unroll
    for (int i = 0; i < 4; ++i) {
        int rb = (wave * 4 + i) * 2;
        int r  = rb + (lane >> 5);
        int cs = (lane & 31) ^ (r & 7);
        gl_lds16(&P.Gt[p][(size_t)r * 256 + cs * 8], &Bw[rb][0]);
    }
    for (int rr = 0; rr < 8; ++rr) {
        int r  = wave * 8 + rr;
        int gr = row0 + r;
        float a0 = 0.f, a1 = 0.f, a2 = 0.f, a3 = 0.f;
        if (gr < n) {
            int i = rowptr[gr], s1 = rowptr[gr + 1];
            for (; i + 2 <= s1; i += 2) {
                int c0 = col[i], c1 = col[i + 1];
                uint2 v0 = *(const uint2*)(Mb + (size_t)c0 * 256 + lane * 4);
                uint2 v1 = *(const uint2*)(Mb + (size_t)c1 * 256 + lane * 4);
                a0 += bf2f(v0.x & 0xffffu) + bf2f(v1.x & 0xffffu);
                a1 += bf2f(v0.x >> 16)     + bf2f(v1.x >> 16);
                a2 += bf2f(v0.y & 0xffffu) + bf2f(v1.y & 0xffffu);
                a3 += bf2f(v0.y >> 16)     + bf2f(v1.y >> 16);
            }
            if (i < s1) {
                uint2 v0 = *(const uint2*)(Mb + (size_t)col[i] * 256 + lane * 4);
                a0 += bf2f(v0.x & 0xffffu); a1 += bf2f(v0.x >> 16);
                a2 += bf2f(v0.y & 0xffffu); a3 += bf2f(v0.y >> 16);
            }
        }
        uint2 o;
        o.x = pk2(lrelu(a0), lrelu(a1));
        o.y = pk2(lrelu(a2), lrelu(a3));
        *(uint2*)&Hl[r][((lane >> 1) ^ (r & 7)) * 8 + (lane & 1) * 4] = o;
    }
    __syncthreads();

    const int fr = lane & 15, fk = lane >> 4;
    const int rt = wave >> 1, nh = wave & 1;
    f32x4 acc[2] = {};
    #pragma unroll
    for (int kk = 0; kk < 8; ++kk) {
        const int ch = ((kk * 4 + fk) ^ (fr & 7)) * 8;
        short8 a_ = *(const short8*)&Hl[rt * 16 + fr][ch];
        #pragma unroll
        for (int j = 0; j < 2; ++j) {
            short8 b_ = *(const short8*)&Bw[(nh * 2 + j) * 16 + fr][ch];
            acc[j] = __builtin_amdgcn_mfma_f32_16x16x32_bf16(a_, b_, acc[j], 0, 0, 0);
        }
    }
    #pragma unroll
    for (int q = 0; q < 4; ++q) {
        int r = row0 + rt * 16 + fk * 4 + q;
        if (r >= n) continue;
        #pragma unroll
        for (int j = 0; j < 2; ++j) {
            int c = (nh * 2 + j) * 16 + fr;
            float xh = bf2f(P.XH[p][(size_t)r * 64 + c]);
            P.Xout[p][(size_t)r * 64 + c] =
                f2bf(lrelu(acc[j][q] + P.gb[p][c] + xh));
        }
    }
}

// ======== layer 2 fused (re-associated conv), bf16 out — unchanged ========
struct GCLG {
    const us* Xin[2]; const us* Ct[2]; const us* Lt[2]; const us* Gt[2];
    const float* lb[2]; const float* gb[2];
    us* Xout[2];
};

// body macro shared by pair & final kernels; PP = modality, RES = f32 out[4][4]
#define GCLG_PHASE(PP, RES, Xin_, Ct_, Lt_, Gt_, lb_, gb_)                     \
    {                                                                          \
        _Pragma("unroll")                                                      \
        for (int i = 0; i < 2; ++i) {                                          \
            int rb = (wave * 2 + i) * 8;                                       \
            int r  = rb + (lane >> 3);                                         \
            int cs = (lane & 7) ^ (r & 7);                                     \
            int rc = min(row0 + r, n - 1);                                     \
            gl_lds16(&Xin_[(size_t)rc * 64 + cs * 8], &Xl[rb][0]);             \
        }                                                                      \
        {                                                                      \
            int rb = wave * 8;                                                 \
            int r  = rb + (lane >> 3);                                         \
            int cs = (lane & 7) ^ (r & 7);                                     \
            gl_lds16(&Ct_[(size_t)r * 64 + cs * 8], &Bc[rb][0]);               \
            gl_lds16(&Lt_[(size_t)r * 64 + cs * 8], &Blw[rb][0]);              \
            gl_lds16(&Gt_[(size_t)r * 64 + cs * 8], &Bg[rb][0]);               \
        }                                                                      \
        for (int rr = 0; rr < 8; ++rr) {                                       \
            int r  = wave * 16 + rr * 2 + half;                                \
            int gr = row0 + r;                                                 \
            float a0 = 0.f, a1 = 0.f;                                          \
            int i = 0, s1 = 0;                                                 \
            if (gr < n) { i = rowptr[gr]; s1 = rowptr[gr + 1]; }               \
            for (; i + 2 <= s1; i += 2) {                                      \
                unsigned v0 = *(const unsigned*)(Xin_ + (size_t)col[i] * 64 + hl * 2);      \
                unsigned v1 = *(const unsigned*)(Xin_ + (size_t)col[i + 1] * 64 + hl * 2);  \
                a0 += bf2f(v0 & 0xffffu) + bf2f(v1 & 0xffffu);                 \
                a1 += bf2f(v0 >> 16)     + bf2f(v1 >> 16);                     \
            }                                                                  \
            if (i < s1) {                                                      \
                unsigned v0 = *(const unsigned*)(Xin_ + (size_t)col[i] * 64 + hl * 2);      \
                a0 += bf2f(v0 & 0xffffu); a1 += bf2f(v0 >> 16);                \
            }                                                                  \
            *(unsigned*)&Sl[r][((hl >> 2) ^ (r & 7)) * 8 + (hl & 3) * 2] = pk2(a0, a1);     \
        }                                                                      \
        __syncthreads();                                                       \
        f32x4 aC[4] = {}, aL[4] = {};                                          \
        _Pragma("unroll")                                                      \
        for (int kk = 0; kk < 2; ++kk) {                                       \
            const int ch = ((kk * 4 + fk) ^ (fr & 7)) * 8;                     \
            short8 as = *(const short8*)&Sl[wave * 16 + fr][ch];               \
            short8 ax = *(const short8*)&Xl[wave * 16 + fr][ch];               \
            _Pragma("unroll")                                                  \
            for (int nn = 0; nn < 4; ++nn) {                                   \
                short8 bc = *(const short8*)&Bc[nn * 16 + fr][ch];             \
                short8 bl = *(const short8*)&Blw[nn * 16 + fr][ch];            \
                aC[nn] = __builtin_amdgcn_mfma_f32_16x16x32_bf16(as, bc, aC[nn], 0, 0, 0);  \
                aL[nn] = __builtin_amdgcn_mfma_f32_16x16x32_bf16(ax, bl, aL[nn], 0, 0, 0);  \
            }                                                                  \
        }                                                                      \
        _Pragma("unroll")                                                      \
        for (int nn = 0; nn < 4; ++nn) {                                       \
            _Pragma("unroll")                                                  \
            for (int q = 0; q < 4; ++q) {                                      \
                int r = wave * 16 + fk * 4 + q;                                \
                int c = nn * 16 + fr;                                          \
                Hl[r][((c >> 3) ^ (r & 7)) * 8 + (c & 7)] = f2bf(lrelu(aC[nn][q]));         \
            }                                                                  \
        }                                                                      \
        __syncthreads();                                                       \
        f32x4 aG[4] = {};                                                      \
        _Pragma("unroll")                                                      \
        for (int kk = 0; kk < 2; ++kk) {                                       \
            const int ch = ((kk * 4 + fk) ^ (fr & 7)) * 8;                     \
            short8 ah = *(const short8*)&Hl[wave * 16 + fr][ch];               \
            _Pragma("unroll")                                                  \
            for (int nn = 0; nn < 4; ++nn) {                                   \
                short8 bg = *(const short8*)&Bg[nn * 16 + fr][ch];             \
                aG[nn] = __builtin_amdgcn_mfma_f32_16x16x32_bf16(ah, bg, aG[nn], 0, 0, 0);  \
            }                                                                  \
        }                                                                      \
        _Pragma("unroll")                                                      \
        for (int q = 0; q < 4; ++q) {                                          \
            int r = row0 + wave * 16 + fk * 4 + q;                             \
            _Pragma("unroll")                                                  \
            for (int nn = 0; nn < 4; ++nn) {                                   \
                int c = nn * 16 + fr;                                          \
                float xhat = lrelu(aL[nn][q] + lb_[c]) +                       \
                             ((r < n) ? id_emb[(size_t)r * 64 + c] : 0.f);     \
                RES[nn][q] = lrelu(aG[nn][q] + gb_[c] + xhat);                 \
            }                                                                  \
        }                                                                      \
    }

__global__ __launch_bounds__(512)
void gather_clg64(GCLG P, const float* __restrict__ id_emb,
                  const int* __restrict__ rowptr, const int* __restrict__ col, int n)
{
    __shared__ __align__(16) us Sl[128][64];
    __shared__ __align__(16) us Xl[128][64];
    __shared__ __align__(16) us Hl[128][64];
    __shared__ __align__(16) us Bc[64][64];
    __shared__ __align__(16) us Blw[64][64];
    __shared__ __align__(16) us Bg[64][64];
    const int p = blockIdx.y;
    const int t = threadIdx.x, wave = t >> 6, lane = t & 63;
    const int row0 = blockIdx.x * 128;
    const int half = lane >> 5, hl = lane & 31;
    const int fr = lane & 15, fk = lane >> 4;

    float res[4][4];
    GCLG_PHASE(p, res, P.Xin[p], P.Ct[p], P.Lt[p], P.Gt[p], P.lb[p], P.gb[p])

    #pragma unroll
    for (int q = 0; q < 4; ++q) {
        int r = row0 + wave * 16 + fk * 4 + q;
        if (r >= n) continue;
        #pragma unroll
        for (int nn = 0; nn < 4; ++nn)
            P.Xout[p][(size_t)r * 64 + nn * 16 + fr] = f2bf(res[nn][q]);
    }
}

// ======== layer 3 fused + final average: both modalities per block, f32 out ========
__global__ __launch_bounds__(512)
void gather_clg64_final(GCLG P, const float* __restrict__ id_emb,
                        const int* __restrict__ rowptr, const int* __restrict__ col,
                        float* __restrict__ out, int n)
{
    __shared__ __align__(16) us Sl[128][64];
    __shared__ __align__(16) us Xl[128][64];
    __shared__ __align__(16) us Hl[128][64];
    __shared__ __align__(16) us Bc[64][64];
    __shared__ __align__(16) us Blw[64][64];
    __shared__ __align__(16) us Bg[64][64];
    const int t = threadIdx.x, wave = t >> 6, lane = t & 63;
    const int row0 = blockIdx.x * 128;
    const int half = lane >> 5, hl = lane & 31;
    const int fr = lane & 15, fk = lane >> 4;

    float r0[4][4], r1[4][4];
    GCLG_PHASE(0, r0, P.Xin[0], P.Ct[0], P.Lt[0], P.Gt[0], P.lb[0], P.gb[0])
    __syncthreads();   // all waves done reading phase-0 LDS before restaging
    GCLG_PHASE(1, r1, P.Xin[1], P.Ct[1], P.Lt[1], P.Gt[1], P.lb[1], P.gb[1])

    // out = (v + t) / 2, f32 (one less bf16 rounding than before)
    #pragma unroll
    for (int q = 0; q < 4; ++q) {
        int r = row0 + wave * 16 + fk * 4 + q;
        if (r >= n) continue;
        #pragma unroll
        for (int nn = 0; nn < 4; ++nn)
            out[(size_t)r * 64 + nn * 16 + fr] = 0.5f * (r0[nn][q] + r1[nn][q]);
    }
}
#undef GCLG_PHASE

// ---------------- fused prep: weight convert + dst histogram + pref L2-norm ----------------

struct WtJob  { const float* w; us* wt; int K; int Nc; };
struct PrepJobs {
    WtJob j[20];
    int   joff[21];        // cumulative block offsets for convert jobs
    int   hist_blocks;     // ceil(nE/256)
    const int* dst; int* deg; int nE;
    const float* pref[2]; us* xb[2];   // norm_pref: 10000 blocks per modality
};

__global__ __launch_bounds__(256)
void prep(PrepJobs P)
{
    int b = blockIdx.x;
    const int t = threadIdx.x;
    if (b < P.joff[20]) {
        // weight convert: find job (<=20 iters, scalar)
        int jj = 0;
        while (P.joff[jj + 1] <= b) ++jj;
        WtJob jb = P.j[jj];
        int i = (b - P.joff[jj]) * 256 + t;
        if (i < jb.K * jb.Nc) {
            int c = i / jb.K, k = i - c * jb.K;
            jb.wt[i] = f2bf(jb.w[(size_t)k * jb.Nc + c]);
        }
        return;
    }
    b -= P.joff[20];
    if (b < P.hist_blocks) {
        int e = b * 256 + t;
        if (e < P.nE) atomicAdd(&P.deg[P.dst[e]], 1);
        return;
    }
    b -= P.hist_blocks;
    // norm_pref: blocks [0, 20000): p = b/10000, 4 rows/block
    int p   = b / 10000;
    int row = (b - p * 10000) * 4 + (t >> 6);
    int lane = t & 63;
    if (row >= NUC) return;
    float4 v = ((const float4*)(P.pref[p] + (size_t)row * 256))[lane];
    float s = v.x * v.x + v.y * v.y + v.z * v.z + v.w * v.w;
    #pragma unroll
    for (int off = 32; off; off >>= 1) s += __shfl_xor(s, off);
    float scale = 1.f / fmaxf(sqrtf(s), 1e-12f);
    uint2 o;
    o.x = pk2(v.x * scale, v.y * scale);
    o.y = pk2(v.z * scale, v.w * scale);
    ((uint2*)(P.xb[p] + (size_t)row * 256))[lane] = o;
}

// ---------------- CSR scan chain (unchanged) ----------------

__global__ __launch_bounds__(256)
void scan_local(const int* __restrict__ deg, int* __restrict__ tmp,
                int* __restrict__ bsum, int n)
{
    __shared__ int s[256];
    int b = blockIdx.x, t = threadIdx.x;
    int base = b * 1024 + t * 4;
    int v[4];
    #pragma unroll
    for (int j = 0; j < 4; ++j) v[j] = (base + j < n) ? deg[base + j] : 0;
    int tsum = v[0] + v[1] + v[2] + v[3];
    s[t] = tsum;
    __syncthreads();
    for (int off = 1; off < 256; off <<= 1) {
        int x = (t >= off) ? s[t - off] : 0;
        __syncthreads();
        s[t] += x;
        __syncthreads();
    }
    int run = s[t] - tsum;
    #pragma unroll
    for (int j = 0; j < 4; ++j) {
        if (base + j < n) tmp[base + j] = run;
        run += v[j];
    }
    if (t == 255) bsum[b] = s[255];
}

__global__ __launch_bounds__(256)
void add_off2(const int* __restrict__ tmp, const int* __restrict__ bsum,
              int* __restrict__ rowptr, int* __restrict__ cursor, int n, int total)
{
    __shared__ int sp;
    if (threadIdx.x == 0) {
        int c = (blockIdx.x * 256) >> 10;
        int s = 0;
        for (int i = 0; i < c; ++i) s += bsum[i];
        sp = s;
    }
    __syncthreads();
    int i = blockIdx.x * 256 + threadIdx.x;
    if (i < n) {
        int v = tmp[i] + sp;
        rowptr[i] = v;
        cursor[i] = v;
    }
    if (i == 0) rowptr[n] = total;
}

__global__ __launch_bounds__(256)
void fill_col(const int* __restrict__ src, const int* __restrict__ dst,
              int* __restrict__ cursor, int* __restrict__ col, int nE)
{
    int e = blockIdx.x * 256 + threadIdx.x;
    if (e >= nE) return;
    int p = atomicAdd(&cursor[dst[e]], 1);
    col[p] = src[e];
}

extern "C" void kernel_launch(void* const* d_in, const int* in_sizes, int n_in,
                              void* d_out, int out_size, void* d_ws, size_t ws_size,
                              hipStream_t stream)
{
    const float* id_emb = (const float*)d_in[2];
    const int*   edge   = (const int*)d_in[3];
    const int nE = in_sizes[3] / 2;
    const int* srcp = edge;
    const int* dstp = edge + nE;

    // Workspace layout (XH bf16)
    us* ub = (us*)d_ws;
    us* XH_[2] = { ub, ub + (size_t)NC * 64 };
    us* Xb_[2] = { XH_[1] + (size_t)NC * 64,
                   XH_[1] + (size_t)NC * 64 + (size_t)NC * 256 };
    us* Xc_[2] = { Xb_[1] + (size_t)NC * 256,
                   Xb_[1] + (size_t)NC * 256 + (size_t)NC * 64 };
    us* Xd_[2] = { Xc_[1] + (size_t)NC * 64,
                   Xc_[1] + (size_t)NC * 64 + (size_t)NC * 64 };
    us* Mb_[2] = { Xd_[1] + (size_t)NC * 64,
                   Xd_[1] + (size_t)NC * 64 + (size_t)NC * 256 };
    us* Wt = Mb_[1] + (size_t)NC * 256;
    int* iw = (int*)(Wt + 1001472);
    int* deg    = iw;
    int* tmp    = deg    + NC;
    int* rowptr = tmp    + NC;
    int* cursor = rowptr + NC + 1;
    int* bsum   = cursor + NC;
    int* col    = bsum   + 256;

    const int nchunks = (NC + 1023) / 1024;

    // per-modality weight order: mlp, conv1, conv2, conv3, lin1, lin2, lin3, g1, g2, g3
    const int kn[10][2] = {{0, 256}, {256, 256}, {64, 64}, {64, 64}, {256, 64},
                           {64, 64}, {64, 64}, {256, 64}, {64, 64}, {64, 64}};
    const int widx[10] = {1, 3, 4, 5, 6, 8, 10, 12, 14, 16};
    PrepJobs PJ = {};
    us* WtP[2][10];
    us* wp = Wt;
    int FD[2];
    int cum = 0;
    for (int p = 0; p < 2; ++p) {
        const int base = 4 + 18 * p;
        FD[p] = in_sizes[p] / NIC;                 // 2048 / 768
        for (int j = 0; j < 10; ++j) {
            int K = (j == 0) ? FD[p] : kn[j][0];
            int Nc = kn[j][1];
            int idx = p * 10 + j;
            PJ.j[idx] = WtJob{(const float*)d_in[base + widx[j]], wp, K, Nc};
            PJ.joff[idx] = cum;
            cum += (K * Nc + 255) / 256;
            WtP[p][j] = wp;
            wp += (size_t)K * Nc;
            wp = (us*)(((size_t)wp + 15) & ~(size_t)15);
        }
    }
    PJ.joff[20] = cum;
    PJ.hist_blocks = (nE + 255) / 256;
    PJ.dst = dstp; PJ.deg = deg; PJ.nE = nE;
    PJ.pref[0] = (const float*)d_in[4];
    PJ.pref[1] = (const float*)d_in[22];
    PJ.xb[0] = Xb_[0]; PJ.xb[1] = Xb_[1];
    const int prep_blocks = cum + PJ.hist_blocks + 20000;

    // prep (convert + hist + norm_pref) after deg zeroing
    hipMemsetAsync(deg, 0, NC * sizeof(int), stream);
    prep<<<prep_blocks, 256, 0, stream>>>(PJ);
    scan_local<<<nchunks, 256, 0, stream>>>(deg, tmp, bsum, NC);
    add_off2<<<(NC + 255) / 256, 256, 0, stream>>>(tmp, bsum, rowptr, cursor, NC, nE);
    fill_col<<<(nE + 255) / 256, 256, 0, stream>>>(srcp, dstp, cursor, col, nE);

    const float* bias_of[2][7];   // mlp_b, lin_b1..3, g_b1..3
    for (int p = 0; p < 2; ++p) {
        const int base = 4 + 18 * p;
        bias_of[p][0] = (const float*)d_in[base + 2];
        bias_of[p][1] = (const float*)d_in[base + 7];
        bias_of[p][2] = (const float*)d_in[base + 9];
        bias_of[p][3] = (const float*)d_in[base + 11];
        bias_of[p][4] = (const float*)d_in[base + 13];
        bias_of[p][5] = (const float*)d_in[base + 15];
        bias_of[p][6] = (const float*)d_in[base + 17];
    }

    const int g128_NI = (NIC + 127) / 128;   // 469
    const int g128_N  = (NC + 127) / 128;    // 782
    const int g64_N   = (NC + 63) / 64;      // 1563

    // ---- both-modality MLP with fused L2-norm (f32 A, depth-2 pipeline) ----
    {
        GPair Pm = {};
        Pm.M = NIC;
        Pm.A[0] = d_in[0];        Pm.A[1] = d_in[1];
        Pm.W[0] = WtP[0][0];      Pm.W[1] = WtP[1][0];
        Pm.bias[0] = bias_of[0][0]; Pm.bias[1] = bias_of[1][0];
        Pm.C[0] = Xb_[0] + (size_t)NUC * 256;
        Pm.C[1] = Xb_[1] + (size_t)NUC * 256;
        Pm.K[0] = FD[0]; Pm.K[1] = FD[1];
        gemm_pair<EPI_NORM, false, true, 4><<<dim3(g128_NI, 2), 256, 0, stream>>>(Pm);
    }

    // ---- layer 1: fused conv1 + lin1 (one GEMM pass over Xb) ----
    {
        GPair Pc = {};
        Pc.M = NC; Pc.K[0] = Pc.K[1] = 256;
        Pc.A[0] = Xb_[0]; Pc.A[1] = Xb_[1];
        Pc.W[0] = WtP[0][1]; Pc.W[1] = WtP[1][1];
        Pc.C[0] = Mb_[0]; Pc.C[1] = Mb_[1];
        Pc.W2[0] = WtP[0][4]; Pc.W2[1] = WtP[1][4];
        Pc.b2[0] = bias_of[0][1]; Pc.b2[1] = bias_of[1][1];
        Pc.extra[0] = id_emb; Pc.extra[1] = id_emb;
        Pc.C2[0] = XH_[0]; Pc.C2[1] = XH_[1];
        gemm_pair<EPI_CLIN, true, true, 4><<<dim3(g128_N, 2), 256, 0, stream>>>(Pc);
    }
    {
        GG256 Pg = {};
        for (int p = 0; p < 2; ++p) {
            Pg.Mb[p] = Mb_[p]; Pg.Gt[p] = WtP[p][7]; Pg.gb[p] = bias_of[p][4];
            Pg.XH[p] = XH_[p]; Pg.Xout[p] = Xc_[p];
        }
        gather_g256<<<dim3(g64_N, 2), 512, 0, stream>>>(Pg, rowptr, col, NC);
    }

    // ---- layer 2: fused kernel (re-associated conv), pair ----
    {
        GCLG Pg = {};
        for (int p = 0; p < 2; ++p) {
            Pg.Xin[p]  = Xc_[p];
            Pg.Xout[p] = Xd_[p];
            Pg.Ct[p] = WtP[p][2];
            Pg.Lt[p] = WtP[p][5];
            Pg.Gt[p] = WtP[p][8];
            Pg.lb[p] = bias_of[p][2];
            Pg.gb[p] = bias_of[p][5];
        }
        gather_clg64<<<dim3(g128_N, 2), 512, 0, stream>>>(Pg, id_emb, rowptr, col, NC);
    }

    // ---- layer 3 + final average: both modalities per block, f32 out ----
    {
        GCLG Pg = {};
        for (int p = 0; p < 2; ++p) {
            Pg.Xin[p]  = Xd_[p];
            Pg.Ct[p] = WtP[p][3];
            Pg.Lt[p] = WtP[p][6];
            Pg.Gt[p] = WtP[p][9];
            Pg.lb[p] = bias_of[p][3];
            Pg.gb[p] = bias_of[p][6];
        }
        gather_clg64_final<<<g128_N, 512, 0, stream>>>(
            Pg, id_emb, rowptr, col, (float*)d_out, NC);
    }
}

// Round 15
// 758.556 us; speedup vs baseline: 1.1016x; 1.1016x over previous
//
#include <hip/hip_runtime.h>
#include <cstddef>
#include <cstdint>

#define NUC 40000
#define NIC 60000
#define NC  100000

typedef short  short8 __attribute__((ext_vector_type(8)));
typedef float  f32x4  __attribute__((ext_vector_type(4)));
typedef unsigned short us;

__device__ __forceinline__ float lrelu(float x) { return x >= 0.f ? x : 0.01f * x; }

__device__ __forceinline__ us f2bf(float f) {
    unsigned int u = __builtin_bit_cast(unsigned int, f);
    u += 0x7fffu + ((u >> 16) & 1u);           // RNE
    return (us)(u >> 16);
}
__device__ __forceinline__ float bf2f(unsigned int v) {
    return __builtin_bit_cast(float, v << 16);
}
__device__ __forceinline__ unsigned pk2(float a, float b) {
    return (unsigned)f2bf(a) | ((unsigned)f2bf(b) << 16);
}

// direct global->LDS DMA, 16B/lane; LDS dest = wave-uniform base + lane*16
__device__ __forceinline__ void gl_lds16(const us* g, us* l) {
    __builtin_amdgcn_global_load_lds(
        (const __attribute__((address_space(1))) unsigned int*)g,
        (__attribute__((address_space(3))) unsigned int*)l,
        16, 0, 0);
}

// counted-wait + raw barrier (T4); sched_barrier(0) fences per learn_hip rule #18.
#define CBAR(N)                                                               \
    asm volatile("s_waitcnt vmcnt(" #N ") lgkmcnt(0)" ::: "memory");          \
    __builtin_amdgcn_sched_barrier(0);                                        \
    __builtin_amdgcn_s_barrier();                                             \
    __builtin_amdgcn_sched_barrier(0);
#define TBAR()                                                                \
    __builtin_amdgcn_sched_barrier(0);                                        \
    __builtin_amdgcn_s_barrier();                                             \
    __builtin_amdgcn_sched_barrier(0);

enum { EPI_NONE = 0, EPI_BIAS = 1, EPI_LIN = 2, EPI_G = 3, EPI_NORM = 4, EPI_CLIN = 5 };

struct GPair {
    const void* A[2]; const us* W[2];
    const float* bias[2]; const float* extra[2];
    void* C[2]; int K[2]; int M;
    // EPI_CLIN extras: second (lin) weight/bias/output
    const us* W2[2]; const float* b2[2]; void* C2[2];
};

// ===== MFMA GEMM pair, counted-vmcnt raw-barrier pipeline (WN=4: 128x256) =====
// R10/R12-proven schedule (NBUF=2, depth-2 A reg prefetch, CBAR 8/12/0).
// EPI_CLIN: also computes XH = lrelu(A@W2 + b2) + id (bf16), wave w owning
// lin rows [w*32, w*32+32). All register indices STATIC (rule #20).
template<int EPI, bool A_BF16, bool OUT_BF16, int WN>
__global__ __launch_bounds__(256, 2)
void gemm_pair(GPair P)
{
    static_assert(WN == 4, "only WN=4 in use");
    constexpr bool CLIN = (EPI == EPI_CLIN);
    constexpr int BM  = 128;
    constexpr int BN  = 256;
    constexpr int MI  = 8;
    constexpr int IA  = BM / 64;
    constexpr int IB  = BN / 64;
    constexpr int NL  = CLIN ? 2 : 1;

    __shared__ __align__(16) us Al[2][BM][32];
    __shared__ __align__(16) us Bl[2][BN][32];
    __shared__ __align__(16) us Ll[CLIN ? 2 : 1][64][32];

    const int p = blockIdx.y;
    const void* Av = P.A[p];
    const us*   Wt = P.W[p];
    const float* bias  = P.bias[p];
    const float* extra = P.extra[p];
    void* Cv = P.C[p];
    const us*    Lt  = P.W2[p];
    const float* lb  = P.b2[p];
    void*        C2v = P.C2[p];
    const int M = P.M, K = P.K[p];

    const int t = threadIdx.x;
    const int wave = t >> 6, lane = t & 63;
    const int wn = wave;
    const int row0 = blockIdx.x * BM;
    const int fr = lane & 15, fk = lane >> 4;

    const float* Af = (const float*)Av;
    const us*    Ab = (const us*)Av;

    float4 sA[4], sB[4];
    f32x4  acc[MI][4] = {};
    f32x4  acc_l[NL][4] = {};

// OOB rows CLAMPED (not skipped): per-wave vmem issue counts must be exact.
#define STAGE_DMA(BUF, K0)                                                     \
    {   const int k0_ = (K0);                                                  \
        _Pragma("unroll")                                                      \
        for (int i = 0; i < IB; ++i) {                                         \
            int rb = (wave * IB + i) * 16;                                     \
            int r  = rb + (lane >> 2);                                         \
            int cs = (lane & 3) ^ (r & 3);                                     \
            gl_lds16(&Wt[(size_t)r * K + k0_ + cs * 8], &Bl[BUF][rb][0]);      \
        }                                                                      \
        if constexpr (A_BF16) {                                                \
            _Pragma("unroll")                                                  \
            for (int i = 0; i < IA; ++i) {                                     \
                int rb = (wave * IA + i) * 16;                                 \
                int r  = rb + (lane >> 2);                                     \
                int cs = (lane & 3) ^ (r & 3);                                 \
                int rc = min(row0 + r, M - 1);                                 \
                gl_lds16(&Ab[(size_t)rc * K + k0_ + cs * 8], &Al[BUF][rb][0]); \
            }                                                                  \
        }                                                                      \
        if constexpr (CLIN) {                                                  \
            int rb = wave * 16;                                                \
            int r  = rb + (lane >> 2);                                         \
            int cs = (lane & 3) ^ (r & 3);                                     \
            gl_lds16(&Lt[(size_t)r * K + k0_ + cs * 8], &Ll[BUF][rb][0]);      \
        }                                                                      \
    }

// f32 A (BM=128): row r = t>>1 (2 threads/row), 16 consecutive floats/thread.
#define AF_LOAD(SL, K0)                                                        \
    {   const int k0_ = (K0);                                                  \
        int r = t >> 1;                                                        \
        int rc = min(row0 + r, M - 1);                                         \
        const float* ap = &Af[(size_t)rc * K + k0_ + (t & 1) * 16];            \
        SL[0] = *(const float4*)ap;                                            \
        SL[1] = *(const float4*)(ap + 4);                                      \
        SL[2] = *(const float4*)(ap + 8);                                      \
        SL[3] = *(const float4*)(ap + 12);                                     \
    }

#define AF_WRITE(SL, BUF)                                                      \
    {   int r  = t >> 1;                                                       \
        int cb = (t & 1) * 2;                                                  \
        uint4 k0v, k1v;                                                        \
        k0v.x = pk2(SL[0].x, SL[0].y);  k0v.y = pk2(SL[0].z, SL[0].w);         \
        k0v.z = pk2(SL[1].x, SL[1].y);  k0v.w = pk2(SL[1].z, SL[1].w);         \
        k1v.x = pk2(SL[2].x, SL[2].y);  k1v.y = pk2(SL[2].z, SL[2].w);         \
        k1v.z = pk2(SL[3].x, SL[3].y);  k1v.w = pk2(SL[3].z, SL[3].w);         \
        *(uint4*)&Al[BUF][r][((cb)     ^ (r & 3)) * 8] = k0v;                  \
        *(uint4*)&Al[BUF][r][((cb + 1) ^ (r & 3)) * 8] = k1v;                  \
    }

#define COMPUTE(BUF)                                                           \
    {   short8 a_[MI], b_[4];                                                  \
        const int ch = (fk ^ (fr & 3)) * 8;                                    \
        _Pragma("unroll")                                                      \
        for (int i = 0; i < MI; ++i)                                           \
            a_[i] = *(const short8*)&Al[BUF][i * 16 + fr][ch];                 \
        _Pragma("unroll")                                                      \
        for (int n = 0; n < 4; ++n)                                            \
            b_[n] = *(const short8*)&Bl[BUF][wn * 64 + n * 16 + fr][ch];       \
        _Pragma("unroll")                                                      \
        for (int i = 0; i < MI; ++i)                                           \
            _Pragma("unroll")                                                  \
            for (int n = 0; n < 4; ++n)                                        \
                acc[i][n] = __builtin_amdgcn_mfma_f32_16x16x32_bf16(           \
                    a_[i], b_[n], acc[i][n], 0, 0, 0);                         \
        if constexpr (CLIN) {                                                  \
            short8 bl_[4];                                                     \
            _Pragma("unroll")                                                  \
            for (int n = 0; n < 4; ++n)                                        \
                bl_[n] = *(const short8*)&Ll[BUF][n * 16 + fr][ch];            \
            _Pragma("unroll")                                                  \
            for (int i = 0; i < MI; ++i) {                                     \
                if ((i >> 1) == wave) {   /* wave-uniform; i is literal */     \
                    _Pragma("unroll")                                          \
                    for (int n = 0; n < 4; ++n)                                \
                        acc_l[i & 1][n] =                                      \
                            __builtin_amdgcn_mfma_f32_16x16x32_bf16(           \
                                a_[i], bl_[n], acc_l[i & 1][n], 0, 0, 0);      \
                }                                                              \
            }                                                                  \
        }                                                                      \
    }

    const int NT = K / 32;

    if constexpr (!A_BF16) {
        // ---- f32 A (4 loads/iter) + B DMA (4/iter); depth-2; NT even >= 4 ----
        AF_LOAD(sA, 0)                 // +4
        AF_LOAD(sB, 32)                // +4
        AF_WRITE(sA, 0)
        STAGE_DMA(0, 0)                // +4
        STAGE_DMA(1, 32)               // +4
        AF_LOAD(sA, 64)                // +4
        CBAR(8)
        COMPUTE(0)
        TBAR()
        for (int tt = 1; tt + 2 < NT; ++tt) {
            STAGE_DMA((tt + 1) & 1, (tt + 1) * 32);
            if (tt & 1) {
                AF_WRITE(sB, 1)
                AF_LOAD(sB, (tt + 2) * 32)
            } else {
                AF_WRITE(sA, 0)
                AF_LOAD(sA, (tt + 2) * 32)
            }
            CBAR(12)
            COMPUTE(tt & 1)
            TBAR()
        }
        STAGE_DMA((NT - 1) & 1, (NT - 1) * 32);
        AF_WRITE(sA, 0)
        CBAR(8)
        COMPUTE(0)
        TBAR()
        AF_WRITE(sB, 1)
        CBAR(0)
        COMPUTE(1)
        TBAR()
    } else {
        // ---- bf16 A: DMA staging; per-wave DMAs/stage: IB+IA(+1 CLIN) ----
        STAGE_DMA(0, 0)
        STAGE_DMA(1, 32)
        if constexpr (CLIN) { CBAR(7) } else { CBAR(6) }
        COMPUTE(0)
        TBAR()
        for (int tt = 1; tt + 1 < NT; ++tt) {
            STAGE_DMA((tt + 1) & 1, (tt + 1) * 32);
            if constexpr (CLIN) { CBAR(7) } else { CBAR(6) }
            COMPUTE(tt & 1)
            TBAR()
        }
        CBAR(0)
        COMPUTE((NT - 1) & 1)
        TBAR()
    }
#undef STAGE_DMA
#undef AF_LOAD
#undef AF_WRITE
#undef COMPUTE

    float* Cf = (float*)Cv;
    us*    Cb = (us*)Cv;

    if constexpr (EPI == EPI_NORM) {
        float (*snorm)[BM] = (float(*)[BM])Al;    // alias: Al dead after loop
        float bv[4];
        #pragma unroll
        for (int nn = 0; nn < 4; ++nn) bv[nn] = bias[wn * 64 + nn * 16 + fr];
        #pragma unroll
        for (int i = 0; i < MI; ++i) {
            #pragma unroll
            for (int q = 0; q < 4; ++q) {
                float pp = 0.f;
                #pragma unroll
                for (int nn = 0; nn < 4; ++nn) {
                    float v = acc[i][nn][q] + bv[nn];
                    acc[i][nn][q] = v;
                    pp += v * v;
                }
                pp += __shfl_xor(pp, 1); pp += __shfl_xor(pp, 2);
                pp += __shfl_xor(pp, 4); pp += __shfl_xor(pp, 8);
                if (fr == 0) snorm[wn][i * 16 + fk * 4 + q] = pp;
            }
        }
        __syncthreads();
        #pragma unroll
        for (int i = 0; i < MI; ++i) {
            #pragma unroll
            for (int q = 0; q < 4; ++q) {
                int rl = i * 16 + fk * 4 + q;
                int r  = row0 + rl;
                if (r >= M) continue;
                float tot = snorm[0][rl] + snorm[1][rl] + snorm[2][rl] + snorm[3][rl];
                float scale = 1.f / fmaxf(sqrtf(tot), 1e-12f);
                #pragma unroll
                for (int nn = 0; nn < 4; ++nn)
                    Cb[(size_t)r * 256 + wn * 64 + nn * 16 + fr] =
                        f2bf(acc[i][nn][q] * scale);
            }
        }
        return;
    }

    if constexpr (CLIN) {
        // conv out: plain bf16 (no bias)
        #pragma unroll
        for (int i = 0; i < MI; ++i) {
            #pragma unroll
            for (int q = 0; q < 4; ++q) {
                int r = row0 + i * 16 + fk * 4 + q;
                if (r >= M) continue;
                #pragma unroll
                for (int n = 0; n < 4; ++n)
                    Cb[(size_t)r * 256 + wn * 64 + n * 16 + fr] = f2bf(acc[i][n][q]);
            }
        }
        // lin out: XH = lrelu(A@L + lb) + id, bf16; wave owns rows wave*32..+32
        us* XHb = (us*)C2v;
        #pragma unroll
        for (int i = 0; i < NL; ++i) {
            #pragma unroll
            for (int q = 0; q < 4; ++q) {
                int r = row0 + wave * 32 + i * 16 + fk * 4 + q;
                if (r >= M) continue;
                #pragma unroll
                for (int n = 0; n < 4; ++n) {
                    int c = n * 16 + fr;
                    float v = lrelu(acc_l[i][n][q] + lb[c]) +
                              extra[(size_t)r * 64 + c];
                    XHb[(size_t)r * 64 + c] = f2bf(v);
                }
            }
        }
        return;
    }

    #pragma unroll
    for (int i = 0; i < MI; ++i) {
        #pragma unroll
        for (int q = 0; q < 4; ++q) {
            int r = row0 + i * 16 + fk * 4 + q;
            if (r >= M) continue;
            #pragma unroll
            for (int n = 0; n < 4; ++n) {
                int c = wn * 64 + n * 16 + fr;
                float v = acc[i][n][q];
                if constexpr (EPI == EPI_BIAS) v += bias[c];
                if constexpr (OUT_BF16) Cb[(size_t)r * BN + c] = f2bf(v);
                else                    Cf[(size_t)r * BN + c] = v;
            }
        }
    }
}

// ======== fused gather + g-GEMM pair, K=256 (layer 1); XH bf16 ========
struct GG256 {
    const us* Mb[2]; const us* Gt[2]; const float* gb[2];
    const us* XH[2]; us* Xout[2];
};
__global__ __launch_bounds__(512)
void gather_g256(GG256 P, const int* __restrict__ rowptr,
                 const int* __restrict__ col, int n)
{
    __shared__ __align__(16) us Hl[64][256];
    __shared__ __align__(16) us Bw[64][256];
    const int p = blockIdx.y;
    const us* Mb = P.Mb[p];
    const int t = threadIdx.x, wave = t >> 6, lane = t & 63;
    const int row0 = blockIdx.x * 64;

    #pragma unroll
    for (int i = 0; i < 4; ++i) {
        int rb = (wave * 4 + i) * 2;
        int r  = rb + (lane >> 5);
        int cs = (lane & 31) ^ (r & 7);
        gl_lds16(&P.Gt[p][(size_t)r * 256 + cs * 8], &Bw[rb][0]);
    }
    for (int rr = 0; rr < 8; ++rr) {
        int r  = wave * 8 + rr;
        int gr = row0 + r;
        float a0 = 0.f, a1 = 0.f, a2 = 0.f, a3 = 0.f;
        if (gr < n) {
            int i = rowptr[gr], s1 = rowptr[gr + 1];
            for (; i + 2 <= s1; i += 2) {
                int c0 = col[i], c1 = col[i + 1];
                uint2 v0 = *(const uint2*)(Mb + (size_t)c0 * 256 + lane * 4);
                uint2 v1 = *(const uint2*)(Mb + (size_t)c1 * 256 + lane * 4);
                a0 += bf2f(v0.x & 0xffffu) + bf2f(v1.x & 0xffffu);
                a1 += bf2f(v0.x >> 16)     + bf2f(v1.x >> 16);
                a2 += bf2f(v0.y & 0xffffu) + bf2f(v1.y & 0xffffu);
                a3 += bf2f(v0.y >> 16)     + bf2f(v1.y >> 16);
            }
            if (i < s1) {
                uint2 v0 = *(const uint2*)(Mb + (size_t)col[i] * 256 + lane * 4);
                a0 += bf2f(v0.x & 0xffffu); a1 += bf2f(v0.x >> 16);
                a2 += bf2f(v0.y & 0xffffu); a3 += bf2f(v0.y >> 16);
            }
        }
        uint2 o;
        o.x = pk2(lrelu(a0), lrelu(a1));
        o.y = pk2(lrelu(a2), lrelu(a3));
        *(uint2*)&Hl[r][((lane >> 1) ^ (r & 7)) * 8 + (lane & 1) * 4] = o;
    }
    __syncthreads();

    const int fr = lane & 15, fk = lane >> 4;
    const int rt = wave >> 1, nh = wave & 1;
    f32x4 acc[2] = {};
    #pragma unroll
    for (int kk = 0; kk < 8; ++kk) {
        const int ch = ((kk * 4 + fk) ^ (fr & 7)) * 8;
        short8 a_ = *(const short8*)&Hl[rt * 16 + fr][ch];
        #pragma unroll
        for (int j = 0; j < 2; ++j) {
            short8 b_ = *(const short8*)&Bw[(nh * 2 + j) * 16 + fr][ch];
            acc[j] = __builtin_amdgcn_mfma_f32_16x16x32_bf16(a_, b_, acc[j], 0, 0, 0);
        }
    }
    #pragma unroll
    for (int q = 0; q < 4; ++q) {
        int r = row0 + rt * 16 + fk * 4 + q;
        if (r >= n) continue;
        #pragma unroll
        for (int j = 0; j < 2; ++j) {
            int c = (nh * 2 + j) * 16 + fr;
            float xh = bf2f(P.XH[p][(size_t)r * 64 + c]);
            P.Xout[p][(size_t)r * 64 + c] =
                f2bf(lrelu(acc[j][q] + P.gb[p][c] + xh));
        }
    }
}

// ======== layers 2,3 fully fused (re-associated conv) ========
struct GCLG {
    const us* Xin[2]; const us* Ct[2]; const us* Lt[2]; const us* Gt[2];
    const float* lb[2]; const float* gb[2];
    us* Xout[2];
};
__global__ __launch_bounds__(512)
void gather_clg64(GCLG P, const float* __restrict__ id_emb,
                  const int* __restrict__ rowptr, const int* __restrict__ col, int n)
{
    __shared__ __align__(16) us Sl[128][64];
    __shared__ __align__(16) us Xl[128][64];
    __shared__ __align__(16) us Hl[128][64];
    __shared__ __align__(16) us Bc[64][64];
    __shared__ __align__(16) us Blw[64][64];
    __shared__ __align__(16) us Bg[64][64];
    const int p = blockIdx.y;
    const us* Xin = P.Xin[p];
    const int t = threadIdx.x, wave = t >> 6, lane = t & 63;
    const int row0 = blockIdx.x * 128;

    #pragma unroll
    for (int i = 0; i < 2; ++i) {
        int rb = (wave * 2 + i) * 8;
        int r  = rb + (lane >> 3);
        int cs = (lane & 7) ^ (r & 7);
        int rc = min(row0 + r, n - 1);
        gl_lds16(&Xin[(size_t)rc * 64 + cs * 8], &Xl[rb][0]);
    }
    {
        int rb = wave * 8;
        int r  = rb + (lane >> 3);
        int cs = (lane & 7) ^ (r & 7);
        gl_lds16(&P.Ct[p][(size_t)r * 64 + cs * 8], &Bc[rb][0]);
        gl_lds16(&P.Lt[p][(size_t)r * 64 + cs * 8], &Blw[rb][0]);
        gl_lds16(&P.Gt[p][(size_t)r * 64 + cs * 8], &Bg[rb][0]);
    }
    const int half = lane >> 5, hl = lane & 31;
    for (int rr = 0; rr < 8; ++rr) {
        int r  = wave * 16 + rr * 2 + half;
        int gr = row0 + r;
        float a0 = 0.f, a1 = 0.f;
        int i = 0, s1 = 0;
        if (gr < n) { i = rowptr[gr]; s1 = rowptr[gr + 1]; }
        for (; i + 2 <= s1; i += 2) {
            unsigned v0 = *(const unsigned*)(Xin + (size_t)col[i] * 64 + hl * 2);
            unsigned v1 = *(const unsigned*)(Xin + (size_t)col[i + 1] * 64 + hl * 2);
            a0 += bf2f(v0 & 0xffffu) + bf2f(v1 & 0xffffu);
            a1 += bf2f(v0 >> 16)     + bf2f(v1 >> 16);
        }
        if (i < s1) {
            unsigned v0 = *(const unsigned*)(Xin + (size_t)col[i] * 64 + hl * 2);
            a0 += bf2f(v0 & 0xffffu); a1 += bf2f(v0 >> 16);
        }
        *(unsigned*)&Sl[r][((hl >> 2) ^ (r & 7)) * 8 + (hl & 3) * 2] = pk2(a0, a1);
    }
    __syncthreads();

    const int fr = lane & 15, fk = lane >> 4;
    f32x4 aC[4] = {}, aL[4] = {};
    #pragma unroll
    for (int kk = 0; kk < 2; ++kk) {
        const int ch = ((kk * 4 + fk) ^ (fr & 7)) * 8;
        short8 as = *(const short8*)&Sl[wave * 16 + fr][ch];
        short8 ax = *(const short8*)&Xl[wave * 16 + fr][ch];
        #pragma unroll
        for (int nn = 0; nn < 4; ++nn) {
            short8 bc = *(const short8*)&Bc[nn * 16 + fr][ch];
            short8 bl = *(const short8*)&Blw[nn * 16 + fr][ch];
            aC[nn] = __builtin_amdgcn_mfma_f32_16x16x32_bf16(as, bc, aC[nn], 0, 0, 0);
            aL[nn] = __builtin_amdgcn_mfma_f32_16x16x32_bf16(ax, bl, aL[nn], 0, 0, 0);
        }
    }
    #pragma unroll
    for (int nn = 0; nn < 4; ++nn) {
        #pragma unroll
        for (int q = 0; q < 4; ++q) {
            int r = wave * 16 + fk * 4 + q;
            int c = nn * 16 + fr;
            Hl[r][((c >> 3) ^ (r & 7)) * 8 + (c & 7)] = f2bf(lrelu(aC[nn][q]));
        }
    }
    __syncthreads();

    f32x4 aG[4] = {};
    #pragma unroll
    for (int kk = 0; kk < 2; ++kk) {
        const int ch = ((kk * 4 + fk) ^ (fr & 7)) * 8;
        short8 ah = *(const short8*)&Hl[wave * 16 + fr][ch];
        #pragma unroll
        for (int nn = 0; nn < 4; ++nn) {
            short8 bg = *(const short8*)&Bg[nn * 16 + fr][ch];
            aG[nn] = __builtin_amdgcn_mfma_f32_16x16x32_bf16(ah, bg, aG[nn], 0, 0, 0);
        }
    }
    #pragma unroll
    for (int q = 0; q < 4; ++q) {
        int r = row0 + wave * 16 + fk * 4 + q;
        if (r >= n) continue;
        #pragma unroll
        for (int nn = 0; nn < 4; ++nn) {
            int c = nn * 16 + fr;
            float xhat = lrelu(aL[nn][q] + P.lb[p][c]) + id_emb[(size_t)r * 64 + c];
            P.Xout[p][(size_t)r * 64 + c] =
                f2bf(lrelu(aG[nn][q] + P.gb[p][c] + xhat));
        }
    }
}

// ---------------- weight pre-convert ----------------

struct WtJob  { const float* w; us* wt; int K; int Nc; };
struct WtJobs { WtJob j[20]; };

__global__ __launch_bounds__(256)
void convert_wt(WtJobs jobs)
{
    WtJob jb = jobs.j[blockIdx.y];
    int n = jb.K * jb.Nc;
    int i = blockIdx.x * 256 + threadIdx.x;
    if (i >= n) return;
    int c = i / jb.K, k = i - c * jb.K;
    jb.wt[i] = f2bf(jb.w[(size_t)k * jb.Nc + c]);
}

// users: Xb[row] = bf16( pref[row] / max(||.||,1e-12) ), pair
struct NP { const float* pref[2]; us* xb[2]; };
__global__ __launch_bounds__(256)
void norm_pref(NP P, int nu)
{
    int p    = blockIdx.y;
    int row  = blockIdx.x * 4 + (threadIdx.x >> 6);
    int lane = threadIdx.x & 63;
    if (row >= nu) return;
    float4 v = ((const float4*)(P.pref[p] + (size_t)row * 256))[lane];
    float s = v.x * v.x + v.y * v.y + v.z * v.z + v.w * v.w;
    #pragma unroll
    for (int off = 32; off; off >>= 1) s += __shfl_xor(s, off);
    float scale = 1.f / fmaxf(sqrtf(s), 1e-12f);
    uint2 o;
    o.x = pk2(v.x * scale, v.y * scale);
    o.y = pk2(v.z * scale, v.w * scale);
    ((uint2*)(P.xb[p] + (size_t)row * 256))[lane] = o;
}

// ---------------- CSR build ----------------

__global__ __launch_bounds__(256)
void hist_dst(const int* __restrict__ dst, int* __restrict__ deg, int nE)
{
    int e = blockIdx.x * 256 + threadIdx.x;
    if (e < nE) atomicAdd(&deg[dst[e]], 1);
}

__global__ __launch_bounds__(256)
void scan_local(const int* __restrict__ deg, int* __restrict__ tmp,
                int* __restrict__ bsum, int n)
{
    __shared__ int s[256];
    int b = blockIdx.x, t = threadIdx.x;
    int base = b * 1024 + t * 4;
    int v[4];
    #pragma unroll
    for (int j = 0; j < 4; ++j) v[j] = (base + j < n) ? deg[base + j] : 0;
    int tsum = v[0] + v[1] + v[2] + v[3];
    s[t] = tsum;
    __syncthreads();
    for (int off = 1; off < 256; off <<= 1) {
        int x = (t >= off) ? s[t - off] : 0;
        __syncthreads();
        s[t] += x;
        __syncthreads();
    }
    int run = s[t] - tsum;
    #pragma unroll
    for (int j = 0; j < 4; ++j) {
        if (base + j < n) tmp[base + j] = run;
        run += v[j];
    }
    if (t == 255) bsum[b] = s[255];
}

__global__ __launch_bounds__(256)
void add_off2(const int* __restrict__ tmp, const int* __restrict__ bsum,
              int* __restrict__ rowptr, int* __restrict__ cursor, int n, int total)
{
    __shared__ int sp;
    if (threadIdx.x == 0) {
        int c = (blockIdx.x * 256) >> 10;
        int s = 0;
        for (int i = 0; i < c; ++i) s += bsum[i];
        sp = s;
    }
    __syncthreads();
    int i = blockIdx.x * 256 + threadIdx.x;
    if (i < n) {
        int v = tmp[i] + sp;
        rowptr[i] = v;
        cursor[i] = v;
    }
    if (i == 0) rowptr[n] = total;
}

__global__ __launch_bounds__(256)
void fill_col(const int* __restrict__ src, const int* __restrict__ dst,
              int* __restrict__ cursor, int* __restrict__ col, int nE)
{
    int e = blockIdx.x * 256 + threadIdx.x;
    if (e >= nE) return;
    int p = atomicAdd(&cursor[dst[e]], 1);
    col[p] = src[e];
}

// out = (v + t) / 2, bf16 inputs -> f32 out
__global__ __launch_bounds__(256)
void combine_avg(const us* __restrict__ a, const us* __restrict__ b,
                 float* __restrict__ o, int n4)
{
    int i = blockIdx.x * 256 + threadIdx.x;
    if (i >= n4) return;
    uint2 x = ((const uint2*)a)[i], y = ((const uint2*)b)[i];
    float4 r;
    r.x = 0.5f * (bf2f(x.x & 0xffffu) + bf2f(y.x & 0xffffu));
    r.y = 0.5f * (bf2f(x.x >> 16)     + bf2f(y.x >> 16));
    r.z = 0.5f * (bf2f(x.y & 0xffffu) + bf2f(y.y & 0xffffu));
    r.w = 0.5f * (bf2f(x.y >> 16)     + bf2f(y.y >> 16));
    ((float4*)o)[i] = r;
}

extern "C" void kernel_launch(void* const* d_in, const int* in_sizes, int n_in,
                              void* d_out, int out_size, void* d_ws, size_t ws_size,
                              hipStream_t stream)
{
    const float* id_emb = (const float*)d_in[2];
    const int*   edge   = (const int*)d_in[3];
    const int nE = in_sizes[3] / 2;
    const int* srcp = edge;
    const int* dstp = edge + nE;

    // Workspace layout (XH bf16)
    us* ub = (us*)d_ws;
    us* XH_[2] = { ub, ub + (size_t)NC * 64 };
    us* Xb_[2] = { XH_[1] + (size_t)NC * 64,
                   XH_[1] + (size_t)NC * 64 + (size_t)NC * 256 };
    us* Xc_[2] = { Xb_[1] + (size_t)NC * 256,
                   Xb_[1] + (size_t)NC * 256 + (size_t)NC * 64 };
    us* Xd_[2] = { Xc_[1] + (size_t)NC * 64,
                   Xc_[1] + (size_t)NC * 64 + (size_t)NC * 64 };
    us* Mb_[2] = { Xd_[1] + (size_t)NC * 64,
                   Xd_[1] + (size_t)NC * 64 + (size_t)NC * 256 };
    us* Wt = Mb_[1] + (size_t)NC * 256;
    int* iw = (int*)(Wt + 1001472);
    int* deg    = iw;
    int* tmp    = deg    + NC;
    int* rowptr = tmp    + NC;
    int* cursor = rowptr + NC + 1;
    int* bsum   = cursor + NC;
    int* col    = bsum   + 256;

    const int nchunks = (NC + 1023) / 1024;

    // per-modality weight order: mlp, conv1, conv2, conv3, lin1, lin2, lin3, g1, g2, g3
    const int kn[10][2] = {{0, 256}, {256, 256}, {64, 64}, {64, 64}, {256, 64},
                           {64, 64}, {64, 64}, {256, 64}, {64, 64}, {64, 64}};
    const int widx[10] = {1, 3, 4, 5, 6, 8, 10, 12, 14, 16};
    WtJobs jobs;
    us* WtP[2][10];
    us* wp = Wt;
    int FD[2];
    for (int p = 0; p < 2; ++p) {
        const int base = 4 + 18 * p;
        FD[p] = in_sizes[p] / NIC;                 // 2048 / 768
        for (int j = 0; j < 10; ++j) {
            int K = (j == 0) ? FD[p] : kn[j][0];
            int Nc = kn[j][1];
            jobs.j[p * 10 + j] = WtJob{(const float*)d_in[base + widx[j]], wp, K, Nc};
            WtP[p][j] = wp;
            wp += (size_t)K * Nc;
            wp = (us*)(((size_t)wp + 15) & ~(size_t)15);
        }
    }
    convert_wt<<<dim3(2048, 20), 256, 0, stream>>>(jobs);

    // CSR
    hipMemsetAsync(deg, 0, NC * sizeof(int), stream);
    hist_dst<<<(nE + 255) / 256, 256, 0, stream>>>(dstp, deg, nE);
    scan_local<<<nchunks, 256, 0, stream>>>(deg, tmp, bsum, NC);
    add_off2<<<(NC + 255) / 256, 256, 0, stream>>>(tmp, bsum, rowptr, cursor, NC, nE);
    fill_col<<<(nE + 255) / 256, 256, 0, stream>>>(srcp, dstp, cursor, col, nE);

    const float* bias_of[2][7];   // mlp_b, lin_b1..3, g_b1..3
    for (int p = 0; p < 2; ++p) {
        const int base = 4 + 18 * p;
        bias_of[p][0] = (const float*)d_in[base + 2];
        bias_of[p][1] = (const float*)d_in[base + 7];
        bias_of[p][2] = (const float*)d_in[base + 9];
        bias_of[p][3] = (const float*)d_in[base + 11];
        bias_of[p][4] = (const float*)d_in[base + 13];
        bias_of[p][5] = (const float*)d_in[base + 15];
        bias_of[p][6] = (const float*)d_in[base + 17];
    }

    const int g128_NI = (NIC + 127) / 128;   // 469
    const int g128_N  = (NC + 127) / 128;    // 782
    const int g64_N   = (NC + 63) / 64;      // 1563

    // ---- both-modality MLP with fused L2-norm (f32 A, depth-2 pipeline) ----
    {
        GPair Pm = {};
        Pm.M = NIC;
        Pm.A[0] = d_in[0];        Pm.A[1] = d_in[1];
        Pm.W[0] = WtP[0][0];      Pm.W[1] = WtP[1][0];
        Pm.bias[0] = bias_of[0][0]; Pm.bias[1] = bias_of[1][0];
        Pm.C[0] = Xb_[0] + (size_t)NUC * 256;
        Pm.C[1] = Xb_[1] + (size_t)NUC * 256;
        Pm.K[0] = FD[0]; Pm.K[1] = FD[1];
        gemm_pair<EPI_NORM, false, true, 4><<<dim3(g128_NI, 2), 256, 0, stream>>>(Pm);
    }
    {
        NP Pn = {};
        Pn.pref[0] = (const float*)d_in[4];
        Pn.pref[1] = (const float*)d_in[22];
        Pn.xb[0] = Xb_[0]; Pn.xb[1] = Xb_[1];
        norm_pref<<<dim3(NUC / 4, 2), 256, 0, stream>>>(Pn, NUC);
    }

    // ---- layer 1: fused conv1 + lin1 (one GEMM pass over Xb) ----
    {
        GPair Pc = {};
        Pc.M = NC; Pc.K[0] = Pc.K[1] = 256;
        Pc.A[0] = Xb_[0]; Pc.A[1] = Xb_[1];
        Pc.W[0] = WtP[0][1]; Pc.W[1] = WtP[1][1];
        Pc.C[0] = Mb_[0]; Pc.C[1] = Mb_[1];
        Pc.W2[0] = WtP[0][4]; Pc.W2[1] = WtP[1][4];
        Pc.b2[0] = bias_of[0][1]; Pc.b2[1] = bias_of[1][1];
        Pc.extra[0] = id_emb; Pc.extra[1] = id_emb;
        Pc.C2[0] = XH_[0]; Pc.C2[1] = XH_[1];
        gemm_pair<EPI_CLIN, true, true, 4><<<dim3(g128_N, 2), 256, 0, stream>>>(Pc);
    }
    {
        GG256 Pg = {};
        for (int p = 0; p < 2; ++p) {
            Pg.Mb[p] = Mb_[p]; Pg.Gt[p] = WtP[p][7]; Pg.gb[p] = bias_of[p][4];
            Pg.XH[p] = XH_[p]; Pg.Xout[p] = Xc_[p];
        }
        gather_g256<<<dim3(g64_N, 2), 512, 0, stream>>>(Pg, rowptr, col, NC);
    }

    // ---- layers 2,3: single fused kernel each (re-associated conv) ----
    for (int l = 1; l < 3; ++l) {
        GCLG Pg = {};
        for (int p = 0; p < 2; ++p) {
            Pg.Xin[p]  = (l == 1) ? Xc_[p] : Xd_[p];
            Pg.Xout[p] = (l == 1) ? Xd_[p] : Xc_[p];
            Pg.Ct[p] = WtP[p][1 + l];
            Pg.Lt[p] = WtP[p][4 + l];
            Pg.Gt[p] = WtP[p][7 + l];
            Pg.lb[p] = bias_of[p][1 + l];
            Pg.gb[p] = bias_of[p][4 + l];
        }
        gather_clg64<<<dim3(g128_N, 2), 512, 0, stream>>>(Pg, id_emb, rowptr, col, NC);
    }

    combine_avg<<<(NC * 64 / 4 + 255) / 256, 256, 0, stream>>>(
        Xc_[0], Xc_[1], (float*)d_out, NC * 64 / 4);
}